// Round 1
// baseline (300.992 us; speedup 1.0000x reference)
//
#include <hip/hip_runtime.h>
#include <stdint.h>

#define INP 128
#define OUTD 128
#define WT_STRIDE 136   // k-stride (bf16 elems) for W' rows: +8 pad, 272 B, keeps ds_read_b128 16B-aligned
#define XT_STRIDE 136   // bf16 elems per x-tile row: 272 B, 16B-aligned reads, b64 writes span even+odd banks

typedef __bf16 bf16x8 __attribute__((ext_vector_type(8)));
typedef __bf16 bf16x4 __attribute__((ext_vector_type(4)));
typedef float  floatx4 __attribute__((ext_vector_type(4)));

// ---------------- threefry2x32 (bit-exact vs jax._src.prng) ----------------
__device__ __forceinline__ uint32_t rotl32(uint32_t v, uint32_t n) {
  return (v << n) | (v >> (32u - n));
}
__device__ __forceinline__ void tf_round(uint32_t& x0, uint32_t& x1, uint32_t r) {
  x0 += x1; x1 = rotl32(x1, r); x1 ^= x0;
}
__device__ void threefry2x32(uint32_t k0, uint32_t k1, uint32_t c0, uint32_t c1,
                             uint32_t& o0, uint32_t& o1) {
  uint32_t k2 = k0 ^ k1 ^ 0x1BD11BDAu;
  uint32_t x0 = c0 + k0, x1 = c1 + k1;
  tf_round(x0,x1,13); tf_round(x0,x1,15); tf_round(x0,x1,26); tf_round(x0,x1,6);
  x0 += k1; x1 += k2 + 1u;
  tf_round(x0,x1,17); tf_round(x0,x1,29); tf_round(x0,x1,16); tf_round(x0,x1,24);
  x0 += k2; x1 += k0 + 2u;
  tf_round(x0,x1,13); tf_round(x0,x1,15); tf_round(x0,x1,26); tf_round(x0,x1,6);
  x0 += k0; x1 += k1 + 3u;
  tf_round(x0,x1,17); tf_round(x0,x1,29); tf_round(x0,x1,16); tf_round(x0,x1,24);
  x0 += k1; x1 += k2 + 4u;
  tf_round(x0,x1,13); tf_round(x0,x1,15); tf_round(x0,x1,26); tf_round(x0,x1,6);
  x0 += k2; x1 += k0 + 5u;
  o0 = x0; o1 = x1;
}

// Giles single-precision erfinv (matches XLA ErfInv32 family; ~1e-6 abs err)
__device__ float erfinv_giles(float x) {
  float w = -logf((1.0f - x) * (1.0f + x));
  float p;
  if (w < 5.0f) {
    w = w - 2.5f;
    p = 2.81022636e-08f;
    p = fmaf(p, w, 3.43273939e-07f);
    p = fmaf(p, w, -3.5233877e-06f);
    p = fmaf(p, w, -4.39150654e-06f);
    p = fmaf(p, w, 0.00021858087f);
    p = fmaf(p, w, -0.00125372503f);
    p = fmaf(p, w, -0.00417768164f);
    p = fmaf(p, w, 0.246640727f);
    p = fmaf(p, w, 1.50140941f);
  } else {
    w = sqrtf(w) - 3.0f;
    p = -0.000200214257f;
    p = fmaf(p, w, 0.000100950558f);
    p = fmaf(p, w, 0.00134934322f);
    p = fmaf(p, w, -0.00367342844f);
    p = fmaf(p, w, 0.00573950773f);
    p = fmaf(p, w, -0.0076224613f);
    p = fmaf(p, w, 0.00943887047f);
    p = fmaf(p, w, 1.00167406f);
    p = fmaf(p, w, 2.83297682f);
  }
  return p * x;
}

__device__ float normal_from_bits(uint32_t bits) {
  const float lo = -0.999999940395355224609375f;
  uint32_t fb = (bits >> 9) | 0x3F800000u;
  float f = __uint_as_float(fb) - 1.0f;
  float u = fmaxf(lo, f * 2.0f + lo);
  return 1.41421356237309515f * erfinv_giles(u);
}

// partitionable-threefry path (verified bit-exact in earlier rounds)
__device__ __forceinline__ uint32_t rand_bits(uint32_t ka, uint32_t kb, int i) {
  uint32_t o0, o1;
  threefry2x32(ka, kb, 0u, (uint32_t)i, o0, o1);
  return o0 ^ o1;
}

// ---------------- fused setup: one launch, 64 blocks x 256 ----------------
// Old setup_reduce was ONE block doing 64 serial strided loads (~latency chain)
// feeding a dependent second launch. Here every block redundantly computes wmax
// (64 KB coalesced float4 reads, 4 independent max accumulators -> a few µs,
// L2-broadcast across blocks); block 0 additionally produces biasEff.
__global__ __launch_bounds__(256) void setup_fused(
    const float* __restrict__ w, const float* __restrict__ bias,
    __bf16* __restrict__ wt, float* __restrict__ biasEff) {
  __shared__ float red[8];
  const int tid = threadIdx.x;

  const floatx4* w4 = (const floatx4*)w;
  float m0 = -3.4e38f, m1 = m0, m2 = m0, m3 = m0;
  #pragma unroll
  for (int it = 0; it < 16; ++it) {
    floatx4 v = w4[it * 256 + tid];
    m0 = fmaxf(m0, v[0]); m1 = fmaxf(m1, v[1]);
    m2 = fmaxf(m2, v[2]); m3 = fmaxf(m3, v[3]);
  }
  float m = fmaxf(fmaxf(m0, m1), fmaxf(m2, m3));
  #pragma unroll
  for (int off = 1; off < 64; off <<= 1) m = fmaxf(m, __shfl_xor(m, off));
  if ((tid & 63) == 0) red[tid >> 6] = m;
  __syncthreads();
  const float wmax = fmaxf(fmaxf(red[0], red[1]), fmaxf(red[2], red[3]));

  // weight noise + quant for this block's 256 weights
  uint32_t k1a, k1b;
  threefry2x32(0u, 1234u, 0u, 0u, k1a, k1b);
  const int i = blockIdx.x * 256 + tid;
  float nrm = normal_from_bits(rand_bits(k1a, k1b, i));
  int r = i >> 7, c = i & 127;   // w[r][c]: r = k (input dim), c = n (output dim)
  float wv = w[i];
  float wq = rintf(fminf(fmaxf(wv * 128.f, -127.f), 127.f)) * 0.0078125f;
  wt[c * WT_STRIDE + r] = (__bf16)(wq + (nrm * wmax) * 0.1f);

  // block 0 (uniform branch): bias max + biasEff
  if (blockIdx.x == 0) {
    float bv = (tid < OUTD) ? bias[tid] : -3.4e38f;
    float bm = bv;
    #pragma unroll
    for (int off = 1; off < 64; off <<= 1) bm = fmaxf(bm, __shfl_xor(bm, off));
    if ((tid & 63) == 0) red[4 + (tid >> 6)] = bm;
    __syncthreads();
    const float bmax = fmaxf(fmaxf(red[4], red[5]), fmaxf(red[6], red[7]));
    if (tid < OUTD) {
      uint32_t k2a, k2b;
      threefry2x32(0u, 1234u, 0u, 1u, k2a, k2b);
      float nrm2 = normal_from_bits(rand_bits(k2a, k2b, tid));
      float bq = rintf(fminf(fmaxf(bv * 128.f, -127.f), 127.f)) * 0.0078125f;
      biasEff[tid] = bq + (nrm2 * bmax) * 0.1f;
    }
  }
}

// ---------------- main ----------------
// R8: occupancy attack. R7 was latency-bound, not BW-bound: 87 µs = 26k cycles
// per 1.3k-cycle tile iteration, MfmaUtil 3.7 / VALUBusy 11 — waves sit in
// vmcnt stalls with only 8 waves/CU (LDS 69120 -> 2 blocks/CU). Fix: quantize
// x in REGISTERS right after the load and stage bf16 (not f32) into LDS.
// sX halves (33792 -> 17408 B), total LDS 52736 -> 3 blocks/CU = 12 waves/CU,
// and the quant VALU chain leaves the ds_read->MFMA critical path.
__device__ __forceinline__ void load_tile_contig(floatx4 v[8], const float* __restrict__ x,
                                                 long tile, int lane) {
  const float* p = x + ((size_t)tile << 11) + lane * 4;   // tile*2048 floats
  #pragma unroll
  for (int k = 0; k < 8; ++k) v[k] = *(const floatx4*)(p + k * 256);
}

// quantize + deposit: instr k holds rows {2k, 2k+1}; lane i -> row 2k+(i>>5), col (i&31)*4
// b64 writes: addr/4 = row*68 + 2c spans even+odd banks -> hits the 2-lanes/bank floor
__device__ __forceinline__ void stage_tile_q(const floatx4 v[8], __bf16* __restrict__ myX,
                                             int lane, float s1, float r1) {
  const int r0 = lane >> 5;
  const int c  = (lane & 31) * 4;
  #pragma unroll
  for (int k = 0; k < 8; ++k) {
    bf16x4 q;
    #pragma unroll
    for (int j = 0; j < 4; ++j)
      q[j] = (__bf16)(rintf(fminf(fmaxf(v[k][j] * s1, -127.f), 127.f)) * r1);
    *(bf16x4*)&myX[(2 * k + r0) * XT_STRIDE + c] = q;
  }
}

__device__ __forceinline__ void compute_tile(
    const __bf16* __restrict__ myX, const __bf16* sW, const float* sBias,
    float* __restrict__ out, long tile, int n16, int quad,
    float s2, float r2) {
  floatx4 acc[8];
  #pragma unroll
  for (int ct = 0; ct < 8; ++ct) acc[ct] = (floatx4)0.0f;

  #pragma unroll
  for (int kc = 0; kc < 4; ++kc) {
    const int kOff = kc * 32 + quad * 8;
    bf16x8 a = *(const bf16x8*)&myX[n16 * XT_STRIDE + kOff];   // ds_read_b128, pre-quantized
    #pragma unroll
    for (int ct = 0; ct < 8; ++ct) {
      bf16x8 wfrag = *(const bf16x8*)&sW[(ct * 16 + n16) * WT_STRIDE + kOff];
      // swapped operands: D[i=outcol][j=batchrow] (transposed C/D)
      acc[ct] = __builtin_amdgcn_mfma_f32_16x16x32_bf16(wfrag, a, acc[ct], 0, 0, 0);
    }
  }

  // epilogue: lane&15 = batch row, quad*4+r = out col -> coalesced dwordx4
  float* orow = out + ((size_t)(tile * 16 + n16) << 7);
  #pragma unroll
  for (int ct = 0; ct < 8; ++ct) {
    const int colBase = ct * 16 + quad * 4;
    floatx4 o;
    #pragma unroll
    for (int r = 0; r < 4; ++r) {
      float h = acc[ct][r] + sBias[colBase + r];
      float tq = fminf(fmaxf(h * s2, -127.0f), 127.0f);
      o[r] = rintf(tq) * r2;
    }
    *(floatx4*)(orow + colBase) = o;
  }
}

// __launch_bounds__(256, 3): 3 waves/EU * 4 EU / 4 waves-per-block = 3 blocks/CU;
// caps VGPR at 168 (R7 used 144 and this version removes inner-loop quant).
__global__ __launch_bounds__(256, 3) void linlayer_main(
    const float* __restrict__ x, const __bf16* __restrict__ wt,
    const float* __restrict__ biasEff, const float* __restrict__ a1p,
    const float* __restrict__ a2p, float* __restrict__ out, int nTiles) {
  __shared__ __attribute__((aligned(16))) __bf16 sW[OUTD * WT_STRIDE];   // 34816 B
  __shared__ __attribute__((aligned(16))) __bf16 sX[4][16 * XT_STRIDE];  // 17408 B
  __shared__ float sBias[OUTD];                                          //   512 B

  const int tid  = threadIdx.x;
  const int wave = tid >> 6;
  const int lane = tid & 63;
  const int n16  = lane & 15;
  const int quad = lane >> 4;

  const int nWaves = gridDim.x * 4;
  const int waveId = blockIdx.x * 4 + wave;
  const long last  = nTiles - 1;

  // prefetch tile 0 BEFORE the W-stage barrier (registers only, no LDS dep)
  floatx4 bufA[8], bufB[8];
  long t = waveId;
  load_tile_contig(bufA, x, (t <= last) ? t : last, lane);

  // stage W' (34816 B) into LDS — once per block
  {
    const uint4* src = (const uint4*)wt;
    uint4* dst = (uint4*)sW;
    for (int i = tid; i < (OUTD * WT_STRIDE * 2) / 16; i += 256) dst[i] = src[i];
  }
  if (tid < OUTD) sBias[tid] = biasEff[tid];

  const float a1 = a1p[0], a2 = a2p[0];
  const float s1 = 128.0f / a1, r1 = a1 * 0.0078125f;  // 32, 1/32 (exact pow2)
  const float s2 = 128.0f / a2, r2 = a2 * 0.0078125f;  // 8, 0.125

  __syncthreads();   // the only barrier

  __bf16* myX = sX[wave];

  while (t <= last) {
    long tn = t + nWaves;
    load_tile_contig(bufB, x, (tn <= last) ? tn : last, lane);  // in flight during tile t
    stage_tile_q(bufA, myX, lane, s1, r1);   // waits vmcnt for bufA only (issued last iter)
    compute_tile(myX, sW, sBias, out, t, n16, quad, s2, r2);
    t = tn;
    if (t > last) break;

    tn = t + nWaves;
    load_tile_contig(bufA, x, (tn <= last) ? tn : last, lane);
    stage_tile_q(bufB, myX, lane, s1, r1);
    compute_tile(myX, sW, sBias, out, t, n16, quad, s2, r2);
    t = tn;
  }
}

extern "C" void kernel_launch(void* const* d_in, const int* in_sizes, int n_in,
                              void* d_out, int out_size, void* d_ws, size_t ws_size,
                              hipStream_t stream) {
  const float* x    = (const float*)d_in[0];
  const float* w    = (const float*)d_in[1];
  const float* bias = (const float*)d_in[2];
  const float* a1   = (const float*)d_in[3];
  const float* a2   = (const float*)d_in[4];
  float* out = (float*)d_out;

  __bf16* wt     = (__bf16*)d_ws;                                   // 34816 B
  float* biasEff = (float*)((char*)d_ws + OUTD * WT_STRIDE * 2);    // +512 B

  const int rows   = in_sizes[0] / INP;   // 262144
  const int nTiles = rows / 16;           // 16384 16-row wave-tiles
  const int grid   = 768;                 // 52736 B LDS -> 3 blocks/CU exactly

  setup_fused<<<64, 256, 0, stream>>>(w, bias, wt, biasEff);
  linlayer_main<<<grid, 256, 0, stream>>>(x, wt, biasEff, a1, a2, out, nTiles);
}